// Round 12
// baseline (475.873 us; speedup 1.0000x reference)
//
#include <hip/hip_runtime.h>
#include <cstdint>
#include <cstddef>

#define MROWS 1024
#define NCOLS 4096
#define KCAP 8

typedef unsigned long long u64;
typedef unsigned int u32;

// Order-preserving float->u32 map (total order, matches score order exactly).
__device__ inline u32 fkey(u32 b) { return (b & 0x80000000u) ? ~b : (b | 0x80000000u); }

// key = (ord << 22) | ((1023-row) << 12) | (4095-col)   (54 bits used)
__device__ inline int key_col(u64 k) { return (NCOLS - 1) - (int)(k & 0xFFFull); }
__device__ inline int key_row(u64 k) { return (MROWS - 1) - (int)((k >> 12) & 0x3FFull); }

// single-wave LDS ordering fence: wait LDS only, do NOT drain vmcnt
#define WAVE_FENCE() __asm__ volatile("s_waitcnt lgkmcnt(0)" ::: "memory")

__device__ inline float wave_sum_f(float v) {
    #pragma unroll
    for (int off = 32; off >= 1; off >>= 1)
        v += __shfl_xor(v, off, 64);
    return v;
}
__device__ inline u64 wave_max_u64(u64 v) {
    #pragma unroll
    for (int off = 32; off >= 1; off >>= 1) {
        u64 o = __shfl_xor(v, off, 64);
        v = o > v ? o : v;
    }
    return v;
}
__device__ inline u64 umax64(u64 a, u64 b) { return a > b ? a : b; }

// ---------------- K1: per-row threshold key-set + exp-sum ---------------------
// Wave-per-row, ZERO block barriers, 256 workgroups. {keys: score > T} is an
// exact prefix of the row's descending key order for any T (fkey monotone;
// ties cannot straddle T). KCAP=8: keys stay 16 VGPRs in the match (the
// r1-proven register budget at 1024 threads). Ladder 3.0/3.25/3.6/4.0 on
// overflow (count monotone in T; ~11% rows retry once, L2-hot reload).
// Short/empty prefix stays exact (row exhausts -> exact fallback in K2).
// N(0,1): E[count@3.0] ~ 5.5.
__global__ __launch_bounds__(256, 4) void k_prep(const float* __restrict__ s,
                                                 float* __restrict__ rowsum,
                                                 u64* __restrict__ keys_g) {
    __shared__ u64 list[4][KCAP];
    __shared__ u32 cnts[4];
    int w = threadIdx.x >> 6, lane = threadIdx.x & 63;
    int r = blockIdx.x * 4 + w;

    const float4* s4 = (const float4*)(s + (size_t)r * NCOLS);
    u64 rowpart = (u64)(MROWS - 1 - r) << 12;
    if (lane == 0) cnts[w] = 0u;
    WAVE_FENCE();

    float acc = 0.0f;
    #pragma unroll
    for (int j = 0; j < 16; ++j) {
        float4 v = s4[lane + j * 64];
        acc += __expf(v.x) + __expf(v.y) + __expf(v.z) + __expf(v.w);
        int c0 = 4 * (lane + j * 64);
        if (v.x > 3.0f) { u32 sl = atomicAdd(&cnts[w], 1u); if (sl < KCAP)
            list[w][sl] = ((u64)fkey(__float_as_uint(v.x)) << 22) | rowpart | (u64)(NCOLS - 1 - (c0 + 0)); }
        if (v.y > 3.0f) { u32 sl = atomicAdd(&cnts[w], 1u); if (sl < KCAP)
            list[w][sl] = ((u64)fkey(__float_as_uint(v.y)) << 22) | rowpart | (u64)(NCOLS - 1 - (c0 + 1)); }
        if (v.z > 3.0f) { u32 sl = atomicAdd(&cnts[w], 1u); if (sl < KCAP)
            list[w][sl] = ((u64)fkey(__float_as_uint(v.z)) << 22) | rowpart | (u64)(NCOLS - 1 - (c0 + 2)); }
        if (v.w > 3.0f) { u32 sl = atomicAdd(&cnts[w], 1u); if (sl < KCAP)
            list[w][sl] = ((u64)fkey(__float_as_uint(v.w)) << 22) | rowpart | (u64)(NCOLS - 1 - (c0 + 3)); }
    }
    acc = wave_sum_f(acc);
    if (lane == 0) rowsum[r] = acc;
    WAVE_FENCE();
    u32 n = cnts[w];

    for (int att = 1; att < 5; ++att) {
        if (n <= KCAP) break;
        float T = att == 1 ? 3.25f : att == 2 ? 3.6f : 4.0f;
        if (lane == 0) cnts[w] = 0u;
        WAVE_FENCE();
        #pragma unroll 4
        for (int j = 0; j < 16; ++j) {
            float4 v = s4[lane + j * 64];
            int c0 = 4 * (lane + j * 64);
            if (v.x > T) { u32 sl = atomicAdd(&cnts[w], 1u); if (sl < KCAP)
                list[w][sl] = ((u64)fkey(__float_as_uint(v.x)) << 22) | rowpart | (u64)(NCOLS - 1 - (c0 + 0)); }
            if (v.y > T) { u32 sl = atomicAdd(&cnts[w], 1u); if (sl < KCAP)
                list[w][sl] = ((u64)fkey(__float_as_uint(v.y)) << 22) | rowpart | (u64)(NCOLS - 1 - (c0 + 1)); }
            if (v.z > T) { u32 sl = atomicAdd(&cnts[w], 1u); if (sl < KCAP)
                list[w][sl] = ((u64)fkey(__float_as_uint(v.z)) << 22) | rowpart | (u64)(NCOLS - 1 - (c0 + 2)); }
            if (v.w > T) { u32 sl = atomicAdd(&cnts[w], 1u); if (sl < KCAP)
                list[w][sl] = ((u64)fkey(__float_as_uint(v.w)) << 22) | rowpart | (u64)(NCOLS - 1 - (c0 + 3)); }
        }
        WAVE_FENCE();
        n = cnts[w];
    }
    if (n > KCAP) n = 0;               // ladder failed (adversarial): empty prefix
    if (lane < KCAP)
        keys_g[(size_t)r * KCAP + lane] = (lane < n) ? list[w][lane] : 0ull;
}

// ---------------- K2: block 0 = match (parallel rounds); rest = policy --------
// Match: the r1-PROVEN shape -- 1024 threads x 1 row x 8 keys in a small array
// (16 VGPRs of keys; resident under the LB(1024) cap). Dominant-edge rounds:
// submit ALL alive keys (required for exactness), commit when row-best ==
// col-best (keys distinct => unique winner). colbest tagged by round so stale
// submissions auto-lose. Exhausted rows -> list-based exact greedy, then a
// full-scan safety net (no-op in practice).
__global__ __launch_bounds__(1024) void k_policy_match(const float* __restrict__ s,
                                                       const int* __restrict__ cont,
                                                       const int* __restrict__ prev,
                                                       const float* __restrict__ rowsum,
                                                       const u64* __restrict__ keys_g,
                                                       float* __restrict__ policy,
                                                       float* __restrict__ actions) {
    __shared__ u64 colbest[NCOLS];             // 32 KiB (match only)
    __shared__ u32 coldone[NCOLS / 32];        // 512 B
    __shared__ u32 rowdone[MROWS / 32];        // 128 B
    __shared__ float act[MROWS];               // 4 KiB
    __shared__ u32 leftrows[64];
    __shared__ int nleft;
    __shared__ float fredf[16];

    int t = threadIdx.x;
    int wid = t >> 6, lane = t & 63;

    if (blockIdx.x != 0) {
        // ---------------- policy row write (1024 thr, 1 float4/thr) -----------
        int r = blockIdx.x - 1;
        const float4* srow4 = (const float4*)(s + (size_t)r * NCOLS);
        float4 v = srow4[t];                   // issue early; flies during reduce
        float sv = rowsum[t];                  // 1024 partials, one per thread
        sv = wave_sum_f(sv);
        if (lane == 0) fredf[wid] = sv;
        __syncthreads();
        float g = 0.0f;
        #pragma unroll
        for (int i = 0; i < 16; ++i) g += fredf[i];   // same order every block
        float inv = 1.0f / g;
        float4* prow4 = (float4*)(policy + (size_t)r * NCOLS);
        float4 p;
        p.x = __expf(v.x) * inv;
        p.y = __expf(v.y) * inv;
        p.z = __expf(v.z) * inv;
        p.w = __expf(v.w) * inv;
        prow4[t] = p;
        return;
    }

    // ---------------- match: thread t owns row t ------------------------------
    #pragma unroll
    for (int i = 0; i < 4; ++i) colbest[t + i * 1024] = 0ull;
    if (t < 128) coldone[t] = 0u;
    if (t < 32) rowdone[t] = 0u;
    if (t == 0) nleft = 0;
    __syncthreads();   // zeroing ordered before the atomics below

    int cgf = cont[t];
    int pv_ = prev[t];
    act[t] = cgf ? (float)pv_ : -1.0f;
    if (cgf) {
        atomicOr(&rowdone[t >> 5], 1u << (t & 31));
        atomicOr(&coldone[pv_ >> 5], 1u << (pv_ & 31));
    }
    bool active = (cgf == 0);

    u64 myk[KCAP];
    {
        const u64* gk = keys_g + (size_t)t * KCAP;
        #pragma unroll
        for (int k = 0; k < KCAP; ++k) myk[k] = gk[k];
    }
    __syncthreads();

    for (int round = 1; round < 500; ++round) {
        u64 tag = (u64)round << 54;
        bool sub = false;
        u64 best = 0ull;
        if (active) {
            u32 cw[KCAP];
            #pragma unroll
            for (int k = 0; k < KCAP; ++k) {
                int c = key_col(myk[k]);       // dead key -> col 4095, harmless
                cw[k] = coldone[c >> 5];
            }
            #pragma unroll
            for (int k = 0; k < KCAP; ++k) {
                int c = key_col(myk[k]);
                if ((cw[k] >> (c & 31)) & 1u) myk[k] = 0ull;
                best = umax64(best, myk[k]);
            }
            if (best == 0ull) {
                active = false;                 // exhausted -> fallback later
            } else {
                sub = true;
                #pragma unroll
                for (int k = 0; k < KCAP; ++k)
                    if (myk[k] != 0ull)
                        atomicMax((u64*)&colbest[key_col(myk[k])], tag | myk[k]);
            }
        }
        __syncthreads();                        // submissions visible
        if (sub && colbest[key_col(best)] == (tag | best)) {
            int c = key_col(best);
            act[t] = (float)c;
            atomicOr(&coldone[c >> 5], 1u << (c & 31));
            atomicOr(&rowdone[t >> 5], 1u << (t & 31));
            active = false;
        }
        int left = __syncthreads_count(active ? 1 : 0);   // commits visible
        if (left == 0) break;
    }
    __syncthreads();

    // ---- exact-greedy fallback over a COLLECTED list of unmatched rows -------
    if (!((rowdone[t >> 5] >> (t & 31)) & 1u)) {
        int i = atomicAdd(&nleft, 1);
        if (i < 64) leftrows[i] = (u32)t;
    }
    __syncthreads();
    int nl = nleft;
    if (nl > 0 && nl <= 64 && t < 64) {        // nl>64 (never): full-scan handles
        for (int guard = 0; guard < 100; ++guard) {
            u64 best = 0ull;
            for (int i = 0; i < nl; ++i) {
                int rr = (int)leftrows[i];
                if ((rowdone[rr >> 5] >> (rr & 31)) & 1u) continue;
                const float* srow = s + (size_t)rr * NCOLS;
                u64 rp = (u64)(MROWS - 1 - rr) << 12;
                for (int c = t; c < NCOLS; c += 64) {
                    if ((coldone[c >> 5] >> (c & 31)) & 1u) continue;
                    u64 kk2 = ((u64)fkey(__float_as_uint(srow[c])) << 22) | rp |
                              (u64)(NCOLS - 1 - c);
                    best = umax64(best, kk2);
                }
            }
            best = wave_max_u64(best);
            if (best == 0ull) break;
            if (t == 0) {
                int row = key_row(best), col = key_col(best);
                rowdone[row >> 5] |= 1u << (row & 31);
                coldone[col >> 5] |= 1u << (col & 31);
                act[row] = (float)col;
            }
            WAVE_FENCE();
        }
    }
    __syncthreads();

    // ---- full-scan safety net (no-op when everything matched) ----------------
    if (t < 64) {
        u32 miss = (t < 32) ? ~rowdone[t] : 0u;
        if (__ballot(miss != 0u) != 0ull) {
            for (int guard = 0; guard < 1200; ++guard) {
                u64 best = 0ull;
                for (int rr = 0; rr < MROWS; ++rr) {
                    if ((rowdone[rr >> 5] >> (rr & 31)) & 1u) continue;
                    const float* srow = s + (size_t)rr * NCOLS;
                    u64 rp = (u64)(MROWS - 1 - rr) << 12;
                    for (int c = t; c < NCOLS; c += 64) {
                        if ((coldone[c >> 5] >> (c & 31)) & 1u) continue;
                        u64 kk2 = ((u64)fkey(__float_as_uint(srow[c])) << 22) | rp |
                                  (u64)(NCOLS - 1 - c);
                        best = umax64(best, kk2);
                    }
                }
                best = wave_max_u64(best);
                if (best == 0ull) break;
                if (t == 0) {
                    int row = key_row(best), col = key_col(best);
                    rowdone[row >> 5] |= 1u << (row & 31);
                    coldone[col >> 5] |= 1u << (col & 31);
                    act[row] = (float)col;
                }
                WAVE_FENCE();
            }
        }
    }
    __syncthreads();
    actions[t] = act[t];
}

extern "C" void kernel_launch(void* const* d_in, const int* in_sizes, int n_in,
                              void* d_out, int out_size, void* d_ws, size_t ws_size,
                              hipStream_t stream) {
    (void)in_sizes; (void)n_in; (void)out_size; (void)ws_size;
    const float* scores = (const float*)d_in[0];
    const int* cont = (const int*)d_in[1];
    const int* prev = (const int*)d_in[2];
    float* out = (float*)d_out;
    float* actions = out;
    float* policy = out + MROWS;

    char* ws = (char*)d_ws;
    float* rowsum = (float*)(ws + 0);            // 1024 f
    u64* keys8 = (u64*)(ws + 8192);              // 1024*8 u64 = 64 KiB

    k_prep<<<MROWS / 4, 256, 0, stream>>>(scores, rowsum, keys8);
    k_policy_match<<<MROWS + 1, 1024, 0, stream>>>(scores, cont, prev, rowsum,
                                                   keys8, policy, actions);
}